// Round 17
// baseline (250.307 us; speedup 1.0000x reference)
//
#include <hip/hip_runtime.h>

typedef unsigned short u16;
typedef __bf16 bf16x8 __attribute__((ext_vector_type(8)));
typedef float f32x4 __attribute__((ext_vector_type(4)));
typedef float f32x16 __attribute__((ext_vector_type(16)));
typedef unsigned short u16x4 __attribute__((ext_vector_type(4)));
typedef unsigned int u32x4 __attribute__((ext_vector_type(4)));

typedef __attribute__((address_space(1))) const unsigned int* gas_t;
typedef __attribute__((address_space(3))) unsigned int* las_t;

__device__ __forceinline__ void gload16(const void* gsrc, void* ldst) {
  __builtin_amdgcn_global_load_lds((gas_t)gsrc, (las_t)ldst, 16, 0, 0);
}

__device__ __forceinline__ u16 f2bf(float f) {
  unsigned u = __builtin_bit_cast(unsigned, f);
  unsigned r = u + 0x7fffu + ((u >> 16) & 1u);
  return (u16)(r >> 16);
}
__device__ __forceinline__ float bf2f(u16 h) {
  unsigned u = ((unsigned)h) << 16;
  return __builtin_bit_cast(float, u);
}
__device__ __forceinline__ unsigned cvtpk(float lo, float hi) {
  unsigned r;
  asm("v_cvt_pk_bf16_f32 %0, %1, %2" : "=v"(r) : "v"(lo), "v"(hi));
  return r;
}
__device__ __forceinline__ float fexp2(float x) {
  return __builtin_amdgcn_exp2f(x);   // raw v_exp_f32 (args bounded; OCML guards not needed)
}

#define QSCALE 0.1803368801111204f   // 0.125 * log2(e): folded into Q at rope time
#define L2E    1.44269504088896f

// ------------- prep1: x->bf16 + wq/wk/wv transpose-convert (fused, r6-verified) -------------
// blocks [0,8192): cvt_x ; [8192,12288): wq ; [12288,13312): wk ; [13312,14336): wv
__global__ __launch_bounds__(256) void prep1(const float* __restrict__ x, u16* __restrict__ xb,
                                             const float* __restrict__ wq, const float* __restrict__ wk,
                                             const float* __restrict__ wv, u16* __restrict__ wT) {
  __shared__ float tile[32][33];
  const int bid = blockIdx.x, tid = threadIdx.x;
  if (bid < 8192) {
    int i = bid * 256 + tid;
    f32x4 v = ((const f32x4*)x)[i];
    u16x4 o = { f2bf(v[0]), f2bf(v[1]), f2bf(v[2]), f2bf(v[3]) };
    ((u16x4*)xb)[i] = o;
    return;
  }
  const float* in; u16* out; int N, bx, by;
  const int K = 2048;
  if (bid < 12288) { int b2 = bid - 8192;  bx = b2 & 63; by = b2 >> 6; in = wq; out = wT;                      N = 2048; }
  else if (bid < 13312) { int b2 = bid - 12288; bx = b2 & 15; by = b2 >> 4; in = wk; out = wT + (size_t)2048 * 2048; N = 512; }
  else { int b2 = bid - 13312; bx = b2 & 15; by = b2 >> 4; in = wv; out = wT + (size_t)2560 * 2048; N = 512; }
  int n0 = bx * 32, k0 = by * 32;
  int tx = tid & 31, ty = tid >> 5;
#pragma unroll
  for (int i = 0; i < 4; ++i)
    tile[ty + i * 8][tx] = in[(size_t)(k0 + ty + i * 8) * N + n0 + tx];
  __syncthreads();
#pragma unroll
  for (int i = 0; i < 4; ++i)
    out[(size_t)(n0 + ty + i * 8) * K + k0 + tx] = f2bf(tile[tx][ty + i * 8]);
}

// ------------- transpose + convert weights (standalone, for wo): [K][N] f32 -> [N][K] bf16 -------------
__global__ __launch_bounds__(256) void transpose_cvt(const float* __restrict__ in, u16* __restrict__ out,
                                                     int K, int N) {
  __shared__ float tile[32][33];
  int n0 = blockIdx.x * 32, k0 = blockIdx.y * 32;
  int tx = threadIdx.x, ty = threadIdx.y; // 32 x 8
#pragma unroll
  for (int i = 0; i < 4; ++i)
    tile[ty + i * 8][tx] = in[(size_t)(k0 + ty + i * 8) * N + n0 + tx];
  __syncthreads();
#pragma unroll
  for (int i = 0; i < 4; ++i)
    out[(size_t)(n0 + ty + i * 8) * K + k0 + tx] = f2bf(tile[tx][ty + i * 8]);
}

// ------------- GEMM: A [M][K] bf16, Bt [N][K] bf16 -> C [M][N] (bf16 or f32) -------------
// m97 layout, BK=64 (32 MFMA per barrier-pair) + T2 XOR swizzle (16-way -> 2-way on
// ds_read_b128): storage chunk s of a row holds logical chunk s^(row&7); applied on the
// global_load_lds SOURCE address (linear LDS dest, rule 21) and on the fragment-read side.
template <int OUTBF>
__global__ __launch_bounds__(256) void gemm_bt(const u16* __restrict__ A, const u16* __restrict__ Bt,
                                               void* __restrict__ Cout, int M, int N, int K) {
  __shared__ u16 As[128 * 64];
  __shared__ u16 Bs[128 * 64];
  const int tid = threadIdx.x;
  const int w = tid >> 6, l = tid & 63, lg = l >> 4, lr = l & 15;
  const int m0 = blockIdx.y * 128, n0 = blockIdx.x * 128;
  const int wr = w >> 1, wc = w & 1;

  // staging: storage chunk c = j*256 + tid; row = c>>3; holds logical chunk (c&7)^(row&7)
  size_t srcA[4], srcB[4];
  int ldst[4];
#pragma unroll
  for (int j = 0; j < 4; ++j) {
    int c = j * 256 + tid;
    int row = c >> 3, kb = (c & 7) ^ (row & 7);
    srcA[j] = (size_t)(m0 + row) * K + kb * 8;
    srcB[j] = (size_t)(n0 + row) * K + kb * 8;
    ldst[j] = (j * 256 + w * 64) * 8;   // wave-uniform element base (lane adds 16B)
  }

  // fragment-read byte offsets: logical chunk kk*4+lg of row -> storage (kk*4+lg)^(lr&7)
  const int lx = lr & 7;
  int aoff[2][4], boff[2][4];
#pragma unroll
  for (int kk = 0; kk < 2; ++kk) {
#pragma unroll
    for (int m = 0; m < 4; ++m)
      aoff[kk][m] = (wr * 64 + m * 16 + lr) * 128 + ((((kk << 2) | lg) ^ lx) << 4);
#pragma unroll
    for (int n = 0; n < 4; ++n)
      boff[kk][n] = (wc * 64 + n * 16 + lr) * 128 + ((((kk << 2) | lg) ^ lx) << 4);
  }

  f32x4 acc[4][4];
#pragma unroll
  for (int m = 0; m < 4; ++m)
#pragma unroll
    for (int n = 0; n < 4; ++n) acc[m][n] = (f32x4){0.f, 0.f, 0.f, 0.f};

  for (int k0 = 0; k0 < K; k0 += 64) {
    __syncthreads();
#pragma unroll
    for (int j = 0; j < 4; ++j) {
      gload16(A + k0 + srcA[j], &As[ldst[j]]);
      gload16(Bt + k0 + srcB[j], &Bs[ldst[j]]);
    }
    __syncthreads();
#pragma unroll
    for (int kk = 0; kk < 2; ++kk) {
      bf16x8 af[4], bf[4];
#pragma unroll
      for (int m = 0; m < 4; ++m)
        af[m] = *(const bf16x8*)((const char*)As + aoff[kk][m]);
#pragma unroll
      for (int n = 0; n < 4; ++n)
        bf[n] = *(const bf16x8*)((const char*)Bs + boff[kk][n]);
      __builtin_amdgcn_s_setprio(1);
#pragma unroll
      for (int m = 0; m < 4; ++m)
#pragma unroll
        for (int n = 0; n < 4; ++n)
          acc[m][n] = __builtin_amdgcn_mfma_f32_16x16x32_bf16(af[m], bf[n], acc[m][n], 0, 0, 0);
      __builtin_amdgcn_s_setprio(0);
    }
  }
#pragma unroll
  for (int m = 0; m < 4; ++m)
#pragma unroll
    for (int n = 0; n < 4; ++n)
#pragma unroll
      for (int r = 0; r < 4; ++r) {
        int row = m0 + wr * 64 + m * 16 + lg * 4 + r;
        int col = n0 + wc * 64 + n * 16 + lr;
        float v = acc[m][n][r];
        if (OUTBF)
          ((u16*)Cout)[(size_t)row * N + col] = f2bf(v);
        else
          ((float*)Cout)[(size_t)row * N + col] = v;
      }
}

// ------------- RoPE: qkv [4096][3072] bf16 -> dst [B][nh][S][64] bf16 (output * scale) -------------
__global__ __launch_bounds__(256) void rope_kernel(const u16* __restrict__ qkv, const float* __restrict__ fcos,
                                                   const float* __restrict__ fsin, u16* __restrict__ dst,
                                                   int nhs /*log2 nheads*/, int col0, float scale) {
  int idx = blockIdx.x * 256 + threadIdx.x;
  int p = idx & 31;
  int h = (idx >> 5) & ((1 << nhs) - 1);
  int t = idx >> (5 + nhs);
  int s = t & 2047, b = t >> 11;
  unsigned v = *(const unsigned*)(qkv + (size_t)t * 3072 + col0 + h * 64 + 2 * p);
  float xr = bf2f((u16)(v & 0xffff)), xi = bf2f((u16)(v >> 16));
  float c = fcos[s * 32 + p], sn = fsin[s * 32 + p];
  float orr = (xr * c - xi * sn) * scale;
  float oii = (xr * sn + xi * c) * scale;
  unsigned o = (unsigned)f2bf(orr) | ((unsigned)f2bf(oii) << 16);
  *(unsigned*)(dst + (((size_t)((b << nhs) + h) * 2048 + s) * 64 + 2 * p)) = o;
}

// ------------- V transpose: qkv cols [2560..3072) -> vT [(b*8+kv)*64+d][S] -------------
// Token (key) columns are PERMUTED within each 16-group (swap bits 2<->3) so that a
// contiguous 16B chunk holds keys in MFMA B-operand slot order (j&3)+8*(j>>2)+4*hi.
__global__ __launch_bounds__(256) void vtrans(const u16* __restrict__ qkv, u16* __restrict__ vT) {
  __shared__ u16 tile[32][33];
  int c0 = blockIdx.x * 32, t0 = blockIdx.y * 32;
  int tx = threadIdx.x, ty = threadIdx.y;
#pragma unroll
  for (int i = 0; i < 4; ++i)
    tile[ty + i * 8][tx] = qkv[(size_t)(t0 + ty + i * 8) * 3072 + 2560 + c0 + tx];
  __syncthreads();
#pragma unroll
  for (int i = 0; i < 4; ++i) {
    int c = c0 + ty + i * 8;
    int tok = t0 + tx;
    int ts = (tok & ~15) | (tok & 3) | ((tok & 4) << 1) | ((tok & 8) >> 1); // swap bits 2,3
    vT[((size_t)((tok >> 11) * 8 + (c >> 6)) * 64 + (c & 63)) * 2048 + (ts & 2047)] = tile[tx][ty + i * 8];
  }
}

// ------------- mask tile flags: one block per qt, LDS reduce (no memset, no global atomics) -------------
__global__ __launch_bounds__(256) void mask_flags(const float* __restrict__ mask, unsigned* __restrict__ Fl) {
  __shared__ unsigned red;
  const int qt = blockIdx.x, tid = threadIdx.x;
  int r_ = tid & 127, half = tid >> 7;
  const float* base = mask + (size_t)(qt * 128 + r_) * 2048 + half * 1024;
  unsigned mymask = 0;
#pragma unroll 4
  for (int g = 0; g < 16; ++g) {
    const f32x4* p = (const f32x4*)(base + g * 64);
    bool any = false;
#pragma unroll
    for (int j = 0; j < 16; ++j) {
      f32x4 v = p[j];
      any |= (v[0] != 0.f) | (v[1] != 0.f) | (v[2] != 0.f) | (v[3] != 0.f);
    }
    if (any) mymask |= 1u << (half * 16 + g);
  }
  if (tid == 0) red = 0;
  __syncthreads();
  atomicOr(&red, mymask);
  __syncthreads();
  if (tid == 0) Fl[qt] = red;
}

// ------------- Flash attention: swapped-QK 32x32 MFMA, MAXLESS softmax, pre-scaled Q -------------
// p = exp2(a - mrun2) directly (mrun2==0 ~always). Mask folds as a += mk*L2E. lrun lane-local;
// cross-half shfl + 1/lrun broadcast via __shfl in the epilogue (no LDS round-trip; no cbuf).
__global__ __launch_bounds__(256, 4) void attn(const u16* __restrict__ Q, const u16* __restrict__ Kb,
                                               const u16* __restrict__ Vt, const float* __restrict__ mask,
                                               const unsigned* __restrict__ Fl, u16* __restrict__ Ao) {
  __shared__ u16 Ks[2][4096];
  __shared__ u16 Vs[2][4096];
  const int bid = blockIdx.x;
  const int qt = bid & 15, h = (bid >> 4) & 31, b = bid >> 9;
  const int kv = h >> 2;
  const int tid = threadIdx.x, w = tid >> 6, l = tid & 63;
  const int lq = l & 31, hi = l >> 5;

  const u16* Qb = Q + ((size_t)((b * 32 + h) * 2048 + qt * 128 + w * 32 + lq)) * 64;
  bf16x8 qf[4];
#pragma unroll
  for (int t = 0; t < 4; ++t)
    qf[t] = *(const bf16x8*)(Qb + t * 16 + hi * 8);

  const u16* Ksrc = Kb + (size_t)(b * 8 + kv) * 2048 * 64;
  const u16* Vsrc = Vt + (size_t)(b * 8 + kv) * 64 * 2048;
  const float* Mrow = mask + (size_t)(qt * 128 + w * 32 + lq) * 2048;
  const unsigned flagbits = Fl[qt];

  const int lx = lq & 7;
  int koff[8];
#pragma unroll
  for (int ks = 0; ks < 2; ++ks)
#pragma unroll
    for (int t = 0; t < 4; ++t)
      koff[ks * 4 + t] = (lq + 32 * ks) * 128 + ((((t << 1) + hi) ^ lx) << 4);
  int voff[8];
#pragma unroll
  for (int ks = 0; ks < 2; ++ks)
#pragma unroll
    for (int t = 0; t < 2; ++t)
#pragma unroll
      for (int dblk = 0; dblk < 2; ++dblk)
        voff[(ks * 2 + t) * 2 + dblk] =
            (lq + 32 * dblk) * 128 + ((((ks << 2) + (t << 1) + hi) ^ lx) << 4);

  size_t kgoff[2], vgoff[2];
  int ldso[2];
#pragma unroll
  for (int j = 0; j < 2; ++j) {
    int c = w * 64 + j * 256 + l;
    int row = c >> 3;
    int sc_ = ((c & 7) ^ (row & 7)) * 8;
    kgoff[j] = (size_t)row * 64 + sc_;
    vgoff[j] = (size_t)row * 2048 + sc_;
    ldso[j] = (w * 64 + j * 256) * 8;
  }

  f32x16 o0, o1, zacc;
#pragma unroll
  for (int i = 0; i < 16; ++i) { o0[i] = 0.f; o1[i] = 0.f; zacc[i] = 0.f; }
  float mrun2 = 0.f, lrun = 0.f;

  auto stage = [&](int kt2, int bu2) {
#pragma unroll
    for (int j = 0; j < 2; ++j) {
      gload16(Ksrc + (size_t)kt2 * 4096 + kgoff[j], &Ks[bu2][ldso[j]]);
      gload16(Vsrc + (size_t)kt2 * 64 + vgoff[j], &Vs[bu2][ldso[j]]);
    }
  };

  stage(0, 0);
  __syncthreads();

  for (int kt = 0; kt < 32; ++kt) {
    const int bu = kt & 1;
    if (kt < 31) stage(kt + 1, bu ^ 1);
    const char* KL = (const char*)Ks[bu];
    const char* VL = (const char*)Vs[bu];
    const bool havemask = (flagbits >> kt) & 1;

#pragma unroll
    for (int ks = 0; ks < 2; ++ks) {
      // ---- QK^T swapped: a[k][q] = sum_d K[k][d] (C*Q[q][d])  (pre-scaled) ----
      __builtin_amdgcn_s_setprio(1);
      bf16x8 kf = *(const bf16x8*)(KL + koff[ks * 4]);
      f32x16 a = __builtin_amdgcn_mfma_f32_32x32x16_bf16(kf, qf[0], zacc, 0, 0, 0);
#pragma unroll
      for (int t = 1; t < 4; ++t) {
        kf = *(const bf16x8*)(KL + koff[ks * 4 + t]);
        a = __builtin_amdgcn_mfma_f32_32x32x16_bf16(kf, qf[t], a, 0, 0, 0);
      }
      __builtin_amdgcn_s_setprio(0);

      // ---- rare path: fold mask (a += mk * log2e) ----
      if (havemask) {
#pragma unroll
        for (int g = 0; g < 4; ++g) {
          f32x4 mk = *(const f32x4*)(Mrow + kt * 64 + ks * 32 + g * 8 + hi * 4);
#pragma unroll
          for (int i = 0; i < 4; ++i) a[g * 4 + i] = fmaf(mk[i], L2E, a[g * 4 + i]);
        }
      }

      // ---- p = exp2(a - mrun2); direct exp when mrun2==0 (~always) ----
      float ps0 = 0.f, ps1 = 0.f, ps2 = 0.f, ps3 = 0.f;
      if (mrun2 == 0.f) {
#pragma unroll
        for (int i = 0; i < 16; i += 4) {
          float p0 = fexp2(a[i]);
          float p1 = fexp2(a[i + 1]);
          float p2 = fexp2(a[i + 2]);
          float p3 = fexp2(a[i + 3]);
          a[i] = p0; a[i + 1] = p1; a[i + 2] = p2; a[i + 3] = p3;
          ps0 += p0; ps1 += p1; ps2 += p2; ps3 += p3;
        }
      } else {
#pragma unroll
        for (int i = 0; i < 16; i += 4) {
          float p0 = fexp2(a[i] - mrun2);
          float p1 = fexp2(a[i + 1] - mrun2);
          float p2 = fexp2(a[i + 2] - mrun2);
          float p3 = fexp2(a[i + 3] - mrun2);
          a[i] = p0; a[i + 1] = p1; a[i + 2] = p2; a[i + 3] = p3;
          ps0 += p0; ps1 += p1; ps2 += p2; ps3 += p3;
        }
      }
      lrun += (ps0 + ps1) + (ps2 + ps3);

      // ---- P -> bf16 (lane-resident; slot j = key (j&3)+8*(j>>2)+4hi), PV via b128 V reads ----
      unsigned uu0 = cvtpk(a[0], a[1]);
      unsigned uu1 = cvtpk(a[2], a[3]);
      unsigned uu2 = cvtpk(a[4], a[5]);
      unsigned uu3 = cvtpk(a[6], a[7]);
      unsigned uu4 = cvtpk(a[8], a[9]);
      unsigned uu5 = cvtpk(a[10], a[11]);
      unsigned uu6 = cvtpk(a[12], a[13]);
      unsigned uu7 = cvtpk(a[14], a[15]);
      __builtin_amdgcn_s_setprio(1);
#pragma unroll
      for (int t = 0; t < 2; ++t) {
        u32x4 wv_;
        if (t == 0) wv_ = (u32x4){uu0, uu1, uu2, uu3};
        else        wv_ = (u32x4){uu4, uu5, uu6, uu7};
        bf16x8 pa = __builtin_bit_cast(bf16x8, wv_);
#pragma unroll
        for (int dblk = 0; dblk < 2; ++dblk) {
          bf16x8 vfrag = *(const bf16x8*)(VL + voff[(ks * 2 + t) * 2 + dblk]);
          if (dblk == 0) o0 = __builtin_amdgcn_mfma_f32_32x32x16_bf16(pa, vfrag, o0, 0, 0, 0);
          else           o1 = __builtin_amdgcn_mfma_f32_32x32x16_bf16(pa, vfrag, o1, 0, 0, 0);
        }
      }
      __builtin_amdgcn_s_setprio(0);
    }

    // ---- overflow guard (wave-uniform, ~never taken): shift scale by 2^-64 ----
    if (__builtin_expect(__any(lrun > 1.0e27f), 0)) {
      const float DS = 5.421010862427522e-20f;  // 2^-64
      mrun2 += 64.0f;
      lrun *= DS;
#pragma unroll
      for (int r = 0; r < 16; ++r) { o0[r] *= DS; o1[r] *= DS; }
    }

    __syncthreads();
  }

  // ---- epilogue: cross-half sum once; 1/lrun broadcast via shfl (lane lq holds row lq) ----
  lrun += __shfl_xor(lrun, 32);
  float linv = 1.0f / lrun;
#pragma unroll
  for (int r = 0; r < 16; ++r) {
    int oq = (r & 3) + 8 * (r >> 2) + 4 * hi;
    float inv = __shfl(linv, oq);
    int srow = qt * 128 + w * 32 + oq;
    size_t tok = (size_t)(b * 2048 + srow);
    Ao[tok * 2048 + h * 64 + lq]      = f2bf(o0[r] * inv);
    Ao[tok * 2048 + h * 64 + 32 + lq] = f2bf(o1[r] * inv);
  }
}

extern "C" void kernel_launch(void* const* d_in, const int* in_sizes, int n_in,
                              void* d_out, int out_size, void* d_ws, size_t ws_size,
                              hipStream_t stream) {
  const float* x    = (const float*)d_in[0];
  const float* fcos = (const float*)d_in[1];
  const float* fsin = (const float*)d_in[2];
  const float* mask = (const float*)d_in[3];
  const float* wq   = (const float*)d_in[4];
  const float* wk   = (const float*)d_in[5];
  const float* wv   = (const float*)d_in[6];
  const float* wo   = (const float*)d_in[7];
  float* out = (float*)d_out;

  // workspace layout (u16 elements), total ~79.7 MB
  u16* ws  = (u16*)d_ws;
  u16* xb  = ws;                       // 8,388,608   x bf16; later reused as attn_out
  u16* wT  = ws + 8388608;             // 6,291,456   wqkvT [3072][2048]; later woT [2048][2048]
  u16* qkv = ws + 14680064;            // 12,582,912  qkv [4096][3072]; head reused as mask flags
  u16* qb  = ws + 27262976;            // 8,388,608   Q [B][32][S][64] (rope'd, *QSCALE)
  u16* kb  = ws + 35651584;            // 2,097,152   K [B][8][S][64]  (rope'd)
  u16* vT  = ws + 37748736;            // 2,097,152   V^T [B*8][64][S] (token cols permuted)
  unsigned* Fl = (unsigned*)qkv;       // 16 u32 (qkv fully consumed before flags are written)

  prep1<<<14336, 256, 0, stream>>>(x, xb, wq, wk, wv, wT);
  gemm_bt<1><<<dim3(24, 32), 256, 0, stream>>>(xb, wT, qkv, 4096, 3072, 2048);
  transpose_cvt<<<dim3(64, 64), dim3(32, 8), 0, stream>>>(wo, wT, 2048, 2048);  // woT (wT reuse)
  rope_kernel<<<16384, 256, 0, stream>>>(qkv, fcos, fsin, qb, 5, 0, QSCALE);
  rope_kernel<<<4096, 256, 0, stream>>>(qkv, fcos, fsin, kb, 3, 2048, 1.0f);
  vtrans<<<dim3(16, 128), dim3(32, 8), 0, stream>>>(qkv, vT);
  mask_flags<<<16, 256, 0, stream>>>(mask, Fl);
  attn<<<1024, 256, 0, stream>>>(qb, kb, vT, mask, Fl, xb);
  gemm_bt<0><<<dim3(16, 32), 256, 0, stream>>>(xb, wT, out, 4096, 2048, 2048);
}

// Round 18
// 227.425 us; speedup vs baseline: 1.1006x; 1.1006x over previous
//
#include <hip/hip_runtime.h>

typedef unsigned short u16;
typedef __bf16 bf16x8 __attribute__((ext_vector_type(8)));
typedef float f32x4 __attribute__((ext_vector_type(4)));
typedef float f32x16 __attribute__((ext_vector_type(16)));
typedef unsigned short u16x4 __attribute__((ext_vector_type(4)));
typedef unsigned int u32x4 __attribute__((ext_vector_type(4)));

typedef __attribute__((address_space(1))) const unsigned int* gas_t;
typedef __attribute__((address_space(3))) unsigned int* las_t;

__device__ __forceinline__ void gload16(const void* gsrc, void* ldst) {
  __builtin_amdgcn_global_load_lds((gas_t)gsrc, (las_t)ldst, 16, 0, 0);
}

__device__ __forceinline__ u16 f2bf(float f) {
  unsigned u = __builtin_bit_cast(unsigned, f);
  unsigned r = u + 0x7fffu + ((u >> 16) & 1u);
  return (u16)(r >> 16);
}
__device__ __forceinline__ float bf2f(u16 h) {
  unsigned u = ((unsigned)h) << 16;
  return __builtin_bit_cast(float, u);
}
__device__ __forceinline__ unsigned cvtpk(float lo, float hi) {
  unsigned r;
  asm("v_cvt_pk_bf16_f32 %0, %1, %2" : "=v"(r) : "v"(lo), "v"(hi));
  return r;
}
__device__ __forceinline__ float fexp2(float x) {
  return __builtin_amdgcn_exp2f(x);   // raw v_exp_f32 (args bounded; OCML guards not needed)
}

#define QSCALE 0.1803368801111204f   // 0.125 * log2(e): folded into Q at rope time
#define L2E    1.44269504088896f

// ---------------- x -> bf16 ----------------
__global__ __launch_bounds__(256) void cvt_x(const float* __restrict__ x, u16* __restrict__ xb) {
  int i = blockIdx.x * 256 + threadIdx.x;
  f32x4 v = ((const f32x4*)x)[i];
  u16x4 o = { f2bf(v[0]), f2bf(v[1]), f2bf(v[2]), f2bf(v[3]) };
  ((u16x4*)xb)[i] = o;
}

// ------------- transpose + convert weights: in [K][N] f32 -> out [N][K] bf16 -------------
__global__ __launch_bounds__(256) void transpose_cvt(const float* __restrict__ in, u16* __restrict__ out,
                                                     int K, int N) {
  __shared__ float tile[32][33];
  int n0 = blockIdx.x * 32, k0 = blockIdx.y * 32;
  int tx = threadIdx.x, ty = threadIdx.y; // 32 x 8
#pragma unroll
  for (int i = 0; i < 4; ++i)
    tile[ty + i * 8][tx] = in[(size_t)(k0 + ty + i * 8) * N + n0 + tx];
  __syncthreads();
#pragma unroll
  for (int i = 0; i < 4; ++i)
    out[(size_t)(n0 + ty + i * 8) * K + k0 + tx] = f2bf(tile[tx][ty + i * 8]);
}

// ------------- GEMM: A [M][K] bf16, Bt [N][K] bf16 -> C [M][N] (bf16 or f32) -------------
// m97 layout, BK=64 (32 MFMA per barrier-pair) + T2 XOR swizzle (16-way -> 2-way on
// ds_read_b128): storage chunk s of a row holds logical chunk s^(row&7); applied on the
// global_load_lds SOURCE address (linear LDS dest, rule 21) and on the fragment-read side.
template <int OUTBF>
__global__ __launch_bounds__(256) void gemm_bt(const u16* __restrict__ A, const u16* __restrict__ Bt,
                                               void* __restrict__ Cout, int M, int N, int K) {
  __shared__ u16 As[128 * 64];
  __shared__ u16 Bs[128 * 64];
  const int tid = threadIdx.x;
  const int w = tid >> 6, l = tid & 63, lg = l >> 4, lr = l & 15;
  const int m0 = blockIdx.y * 128, n0 = blockIdx.x * 128;
  const int wr = w >> 1, wc = w & 1;

  // staging: storage chunk c = j*256 + tid; row = c>>3; holds logical chunk (c&7)^(row&7)
  size_t srcA[4], srcB[4];
  int ldst[4];
#pragma unroll
  for (int j = 0; j < 4; ++j) {
    int c = j * 256 + tid;
    int row = c >> 3, kb = (c & 7) ^ (row & 7);
    srcA[j] = (size_t)(m0 + row) * K + kb * 8;
    srcB[j] = (size_t)(n0 + row) * K + kb * 8;
    ldst[j] = (j * 256 + w * 64) * 8;   // wave-uniform element base (lane adds 16B)
  }

  // fragment-read byte offsets: logical chunk kk*4+lg of row -> storage (kk*4+lg)^(lr&7)
  const int lx = lr & 7;
  int aoff[2][4], boff[2][4];
#pragma unroll
  for (int kk = 0; kk < 2; ++kk) {
#pragma unroll
    for (int m = 0; m < 4; ++m)
      aoff[kk][m] = (wr * 64 + m * 16 + lr) * 128 + ((((kk << 2) | lg) ^ lx) << 4);
#pragma unroll
    for (int n = 0; n < 4; ++n)
      boff[kk][n] = (wc * 64 + n * 16 + lr) * 128 + ((((kk << 2) | lg) ^ lx) << 4);
  }

  f32x4 acc[4][4];
#pragma unroll
  for (int m = 0; m < 4; ++m)
#pragma unroll
    for (int n = 0; n < 4; ++n) acc[m][n] = (f32x4){0.f, 0.f, 0.f, 0.f};

  for (int k0 = 0; k0 < K; k0 += 64) {
    __syncthreads();
#pragma unroll
    for (int j = 0; j < 4; ++j) {
      gload16(A + k0 + srcA[j], &As[ldst[j]]);
      gload16(Bt + k0 + srcB[j], &Bs[ldst[j]]);
    }
    __syncthreads();
#pragma unroll
    for (int kk = 0; kk < 2; ++kk) {
      bf16x8 af[4], bf[4];
#pragma unroll
      for (int m = 0; m < 4; ++m)
        af[m] = *(const bf16x8*)((const char*)As + aoff[kk][m]);
#pragma unroll
      for (int n = 0; n < 4; ++n)
        bf[n] = *(const bf16x8*)((const char*)Bs + boff[kk][n]);
      __builtin_amdgcn_s_setprio(1);
#pragma unroll
      for (int m = 0; m < 4; ++m)
#pragma unroll
        for (int n = 0; n < 4; ++n)
          acc[m][n] = __builtin_amdgcn_mfma_f32_16x16x32_bf16(af[m], bf[n], acc[m][n], 0, 0, 0);
      __builtin_amdgcn_s_setprio(0);
    }
  }
#pragma unroll
  for (int m = 0; m < 4; ++m)
#pragma unroll
    for (int n = 0; n < 4; ++n)
#pragma unroll
      for (int r = 0; r < 4; ++r) {
        int row = m0 + wr * 64 + m * 16 + lg * 4 + r;
        int col = n0 + wc * 64 + n * 16 + lr;
        float v = acc[m][n][r];
        if (OUTBF)
          ((u16*)Cout)[(size_t)row * N + col] = f2bf(v);
        else
          ((float*)Cout)[(size_t)row * N + col] = v;
      }
}

// ------------- RoPE: qkv [4096][3072] bf16 -> dst [B][nh][S][64] bf16 (output * scale) -------------
__global__ __launch_bounds__(256) void rope_kernel(const u16* __restrict__ qkv, const float* __restrict__ fcos,
                                                   const float* __restrict__ fsin, u16* __restrict__ dst,
                                                   int nhs /*log2 nheads*/, int col0, float scale) {
  int idx = blockIdx.x * 256 + threadIdx.x;
  int p = idx & 31;
  int h = (idx >> 5) & ((1 << nhs) - 1);
  int t = idx >> (5 + nhs);
  int s = t & 2047, b = t >> 11;
  unsigned v = *(const unsigned*)(qkv + (size_t)t * 3072 + col0 + h * 64 + 2 * p);
  float xr = bf2f((u16)(v & 0xffff)), xi = bf2f((u16)(v >> 16));
  float c = fcos[s * 32 + p], sn = fsin[s * 32 + p];
  float orr = (xr * c - xi * sn) * scale;
  float oii = (xr * sn + xi * c) * scale;
  unsigned o = (unsigned)f2bf(orr) | ((unsigned)f2bf(oii) << 16);
  *(unsigned*)(dst + (((size_t)((b << nhs) + h) * 2048 + s) * 64 + 2 * p)) = o;
}

// ------------- V transpose: qkv cols [2560..3072) -> vT [(b*8+kv)*64+d][S] -------------
// Token (key) columns are PERMUTED within each 16-group (swap bits 2<->3) so that a
// contiguous 16B chunk holds keys in MFMA B-operand slot order (j&3)+8*(j>>2)+4*hi.
__global__ __launch_bounds__(256) void vtrans(const u16* __restrict__ qkv, u16* __restrict__ vT) {
  __shared__ u16 tile[32][33];
  int c0 = blockIdx.x * 32, t0 = blockIdx.y * 32;
  int tx = threadIdx.x, ty = threadIdx.y;
#pragma unroll
  for (int i = 0; i < 4; ++i)
    tile[ty + i * 8][tx] = qkv[(size_t)(t0 + ty + i * 8) * 3072 + 2560 + c0 + tx];
  __syncthreads();
#pragma unroll
  for (int i = 0; i < 4; ++i) {
    int c = c0 + ty + i * 8;
    int tok = t0 + tx;
    int ts = (tok & ~15) | (tok & 3) | ((tok & 4) << 1) | ((tok & 8) >> 1); // swap bits 2,3
    vT[((size_t)((tok >> 11) * 8 + (c >> 6)) * 64 + (c & 63)) * 2048 + (ts & 2047)] = tile[tx][ty + i * 8];
  }
}

// ------------- mask tile flags: Fl[qt] bit kt = (128q x 64k tile has any nonzero) -------------
__global__ __launch_bounds__(256) void mask_flags(const float* __restrict__ mask, unsigned* __restrict__ Fl) {
  int qt = blockIdx.x, kt = blockIdx.y;
  int t = threadIdx.x;
  int row = qt * 128 + (t >> 1);
  const f32x4* p = (const f32x4*)(mask + (size_t)row * 2048 + kt * 64 + (t & 1) * 32);
  bool any = false;
#pragma unroll
  for (int j = 0; j < 8; ++j) {
    f32x4 v = p[j];
    any |= (v[0] != 0.f) | (v[1] != 0.f) | (v[2] != 0.f) | (v[3] != 0.f);
  }
  if (__any(any) && (t & 63) == 0) atomicOr(&Fl[qt], 1u << kt);
}

// ------------- Flash attention: swapped-QK 32x32 MFMA, MAXLESS softmax, pre-scaled Q -------------
// p = exp2(a - mrun2) directly (mrun2==0 ~always). Mask folds as a += mk*L2E. lrun lane-local;
// cross-half shfl + 1/lrun broadcast via __shfl in the epilogue (no LDS round-trip; no cbuf).
__global__ __launch_bounds__(256, 4) void attn(const u16* __restrict__ Q, const u16* __restrict__ Kb,
                                               const u16* __restrict__ Vt, const float* __restrict__ mask,
                                               const unsigned* __restrict__ Fl, u16* __restrict__ Ao) {
  __shared__ u16 Ks[2][4096];
  __shared__ u16 Vs[2][4096];
  const int bid = blockIdx.x;
  const int qt = bid & 15, h = (bid >> 4) & 31, b = bid >> 9;
  const int kv = h >> 2;
  const int tid = threadIdx.x, w = tid >> 6, l = tid & 63;
  const int lq = l & 31, hi = l >> 5;

  const u16* Qb = Q + ((size_t)((b * 32 + h) * 2048 + qt * 128 + w * 32 + lq)) * 64;
  bf16x8 qf[4];
#pragma unroll
  for (int t = 0; t < 4; ++t)
    qf[t] = *(const bf16x8*)(Qb + t * 16 + hi * 8);

  const u16* Ksrc = Kb + (size_t)(b * 8 + kv) * 2048 * 64;
  const u16* Vsrc = Vt + (size_t)(b * 8 + kv) * 64 * 2048;
  const float* Mrow = mask + (size_t)(qt * 128 + w * 32 + lq) * 2048;
  const unsigned flagbits = Fl[qt];

  const int lx = lq & 7;
  int koff[8];
#pragma unroll
  for (int ks = 0; ks < 2; ++ks)
#pragma unroll
    for (int t = 0; t < 4; ++t)
      koff[ks * 4 + t] = (lq + 32 * ks) * 128 + ((((t << 1) + hi) ^ lx) << 4);
  int voff[8];
#pragma unroll
  for (int ks = 0; ks < 2; ++ks)
#pragma unroll
    for (int t = 0; t < 2; ++t)
#pragma unroll
      for (int dblk = 0; dblk < 2; ++dblk)
        voff[(ks * 2 + t) * 2 + dblk] =
            (lq + 32 * dblk) * 128 + ((((ks << 2) + (t << 1) + hi) ^ lx) << 4);

  size_t kgoff[2], vgoff[2];
  int ldso[2];
#pragma unroll
  for (int j = 0; j < 2; ++j) {
    int c = w * 64 + j * 256 + l;
    int row = c >> 3;
    int sc_ = ((c & 7) ^ (row & 7)) * 8;
    kgoff[j] = (size_t)row * 64 + sc_;
    vgoff[j] = (size_t)row * 2048 + sc_;
    ldso[j] = (w * 64 + j * 256) * 8;
  }

  f32x16 o0, o1, zacc;
#pragma unroll
  for (int i = 0; i < 16; ++i) { o0[i] = 0.f; o1[i] = 0.f; zacc[i] = 0.f; }
  float mrun2 = 0.f, lrun = 0.f;

  auto stage = [&](int kt2, int bu2) {
#pragma unroll
    for (int j = 0; j < 2; ++j) {
      gload16(Ksrc + (size_t)kt2 * 4096 + kgoff[j], &Ks[bu2][ldso[j]]);
      gload16(Vsrc + (size_t)kt2 * 64 + vgoff[j], &Vs[bu2][ldso[j]]);
    }
  };

  stage(0, 0);
  __syncthreads();

  for (int kt = 0; kt < 32; ++kt) {
    const int bu = kt & 1;
    if (kt < 31) stage(kt + 1, bu ^ 1);
    const char* KL = (const char*)Ks[bu];
    const char* VL = (const char*)Vs[bu];
    const bool havemask = (flagbits >> kt) & 1;

#pragma unroll
    for (int ks = 0; ks < 2; ++ks) {
      // ---- QK^T swapped: a[k][q] = sum_d K[k][d] (C*Q[q][d])  (pre-scaled) ----
      __builtin_amdgcn_s_setprio(1);
      bf16x8 kf = *(const bf16x8*)(KL + koff[ks * 4]);
      f32x16 a = __builtin_amdgcn_mfma_f32_32x32x16_bf16(kf, qf[0], zacc, 0, 0, 0);
#pragma unroll
      for (int t = 1; t < 4; ++t) {
        kf = *(const bf16x8*)(KL + koff[ks * 4 + t]);
        a = __builtin_amdgcn_mfma_f32_32x32x16_bf16(kf, qf[t], a, 0, 0, 0);
      }
      __builtin_amdgcn_s_setprio(0);

      // ---- rare path: fold mask (a += mk * log2e) ----
      if (havemask) {
#pragma unroll
        for (int g = 0; g < 4; ++g) {
          f32x4 mk = *(const f32x4*)(Mrow + kt * 64 + ks * 32 + g * 8 + hi * 4);
#pragma unroll
          for (int i = 0; i < 4; ++i) a[g * 4 + i] = fmaf(mk[i], L2E, a[g * 4 + i]);
        }
      }

      // ---- p = exp2(a - mrun2); direct exp when mrun2==0 (~always) ----
      float ps0 = 0.f, ps1 = 0.f, ps2 = 0.f, ps3 = 0.f;
      if (mrun2 == 0.f) {
#pragma unroll
        for (int i = 0; i < 16; i += 4) {
          float p0 = fexp2(a[i]);
          float p1 = fexp2(a[i + 1]);
          float p2 = fexp2(a[i + 2]);
          float p3 = fexp2(a[i + 3]);
          a[i] = p0; a[i + 1] = p1; a[i + 2] = p2; a[i + 3] = p3;
          ps0 += p0; ps1 += p1; ps2 += p2; ps3 += p3;
        }
      } else {
#pragma unroll
        for (int i = 0; i < 16; i += 4) {
          float p0 = fexp2(a[i] - mrun2);
          float p1 = fexp2(a[i + 1] - mrun2);
          float p2 = fexp2(a[i + 2] - mrun2);
          float p3 = fexp2(a[i + 3] - mrun2);
          a[i] = p0; a[i + 1] = p1; a[i + 2] = p2; a[i + 3] = p3;
          ps0 += p0; ps1 += p1; ps2 += p2; ps3 += p3;
        }
      }
      lrun += (ps0 + ps1) + (ps2 + ps3);

      // ---- P -> bf16 (lane-resident; slot j = key (j&3)+8*(j>>2)+4hi), PV via b128 V reads ----
      unsigned uu0 = cvtpk(a[0], a[1]);
      unsigned uu1 = cvtpk(a[2], a[3]);
      unsigned uu2 = cvtpk(a[4], a[5]);
      unsigned uu3 = cvtpk(a[6], a[7]);
      unsigned uu4 = cvtpk(a[8], a[9]);
      unsigned uu5 = cvtpk(a[10], a[11]);
      unsigned uu6 = cvtpk(a[12], a[13]);
      unsigned uu7 = cvtpk(a[14], a[15]);
      __builtin_amdgcn_s_setprio(1);
#pragma unroll
      for (int t = 0; t < 2; ++t) {
        u32x4 wv_;
        if (t == 0) wv_ = (u32x4){uu0, uu1, uu2, uu3};
        else        wv_ = (u32x4){uu4, uu5, uu6, uu7};
        bf16x8 pa = __builtin_bit_cast(bf16x8, wv_);
#pragma unroll
        for (int dblk = 0; dblk < 2; ++dblk) {
          bf16x8 vfrag = *(const bf16x8*)(VL + voff[(ks * 2 + t) * 2 + dblk]);
          if (dblk == 0) o0 = __builtin_amdgcn_mfma_f32_32x32x16_bf16(pa, vfrag, o0, 0, 0, 0);
          else           o1 = __builtin_amdgcn_mfma_f32_32x32x16_bf16(pa, vfrag, o1, 0, 0, 0);
        }
      }
      __builtin_amdgcn_s_setprio(0);
    }

    // ---- overflow guard (wave-uniform, ~never taken): shift scale by 2^-64 ----
    if (__builtin_expect(__any(lrun > 1.0e27f), 0)) {
      const float DS = 5.421010862427522e-20f;  // 2^-64
      mrun2 += 64.0f;
      lrun *= DS;
#pragma unroll
      for (int r = 0; r < 16; ++r) { o0[r] *= DS; o1[r] *= DS; }
    }

    __syncthreads();
  }

  // ---- epilogue: cross-half sum once; 1/lrun broadcast via shfl (lane lq holds row lq) ----
  lrun += __shfl_xor(lrun, 32);
  float linv = 1.0f / lrun;
#pragma unroll
  for (int r = 0; r < 16; ++r) {
    int oq = (r & 3) + 8 * (r >> 2) + 4 * hi;
    float inv = __shfl(linv, oq);
    int srow = qt * 128 + w * 32 + oq;
    size_t tok = (size_t)(b * 2048 + srow);
    Ao[tok * 2048 + h * 64 + lq]      = f2bf(o0[r] * inv);
    Ao[tok * 2048 + h * 64 + 32 + lq] = f2bf(o1[r] * inv);
  }
}

extern "C" void kernel_launch(void* const* d_in, const int* in_sizes, int n_in,
                              void* d_out, int out_size, void* d_ws, size_t ws_size,
                              hipStream_t stream) {
  const float* x    = (const float*)d_in[0];
  const float* fcos = (const float*)d_in[1];
  const float* fsin = (const float*)d_in[2];
  const float* mask = (const float*)d_in[3];
  const float* wq   = (const float*)d_in[4];
  const float* wk   = (const float*)d_in[5];
  const float* wv   = (const float*)d_in[6];
  const float* wo   = (const float*)d_in[7];
  float* out = (float*)d_out;

  // workspace layout (u16 elements), total ~79.7 MB
  u16* ws  = (u16*)d_ws;
  u16* xb  = ws;                       // 8,388,608   x bf16; later reused as attn_out
  u16* wT  = ws + 8388608;             // 6,291,456   wqkvT [3072][2048]; later woT [2048][2048]
  u16* qkv = ws + 14680064;            // 12,582,912  qkv [4096][3072]; head reused as mask flags
  u16* qb  = ws + 27262976;            // 8,388,608   Q [B][32][S][64] (rope'd, *QSCALE)
  u16* kb  = ws + 35651584;            // 2,097,152   K [B][8][S][64]  (rope'd)
  u16* vT  = ws + 37748736;            // 2,097,152   V^T [B*8][64][S] (token cols permuted)
  unsigned* Fl = (unsigned*)qkv;       // 16 u32 (qkv fully consumed before flags are written)

  cvt_x<<<8192, 256, 0, stream>>>(x, xb);
  transpose_cvt<<<dim3(64, 64), dim3(32, 8), 0, stream>>>(wq, wT, 2048, 2048);
  transpose_cvt<<<dim3(16, 64), dim3(32, 8), 0, stream>>>(wk, wT + (size_t)2048 * 2048, 2048, 512);
  transpose_cvt<<<dim3(16, 64), dim3(32, 8), 0, stream>>>(wv, wT + (size_t)2560 * 2048, 2048, 512);
  gemm_bt<1><<<dim3(24, 32), 256, 0, stream>>>(xb, wT, qkv, 4096, 3072, 2048);
  transpose_cvt<<<dim3(64, 64), dim3(32, 8), 0, stream>>>(wo, wT, 2048, 2048);  // woT (wT reuse)
  rope_kernel<<<16384, 256, 0, stream>>>(qkv, fcos, fsin, qb, 5, 0, QSCALE);
  rope_kernel<<<4096, 256, 0, stream>>>(qkv, fcos, fsin, kb, 3, 2048, 1.0f);
  vtrans<<<dim3(16, 128), dim3(32, 8), 0, stream>>>(qkv, vT);
  hipMemsetAsync(Fl, 0, 16 * sizeof(unsigned), stream);   // qkv fully consumed above
  mask_flags<<<dim3(16, 32), 256, 0, stream>>>(mask, Fl);
  attn<<<1024, 256, 0, stream>>>(qb, kb, vT, mask, Fl, xb);
  gemm_bt<0><<<dim3(16, 32), 256, 0, stream>>>(xb, wT, out, 4096, 2048, 2048);
}

// Round 19
// 219.610 us; speedup vs baseline: 1.1398x; 1.0356x over previous
//
#include <hip/hip_runtime.h>

typedef unsigned short u16;
typedef __bf16 bf16x8 __attribute__((ext_vector_type(8)));
typedef float f32x4 __attribute__((ext_vector_type(4)));
typedef float f32x16 __attribute__((ext_vector_type(16)));
typedef unsigned short u16x4 __attribute__((ext_vector_type(4)));
typedef unsigned int u32x4 __attribute__((ext_vector_type(4)));

typedef __attribute__((address_space(1))) const unsigned int* gas_t;
typedef __attribute__((address_space(3))) unsigned int* las_t;

__device__ __forceinline__ void gload16(const void* gsrc, void* ldst) {
  __builtin_amdgcn_global_load_lds((gas_t)gsrc, (las_t)ldst, 16, 0, 0);
}

__device__ __forceinline__ u16 f2bf(float f) {
  unsigned u = __builtin_bit_cast(unsigned, f);
  unsigned r = u + 0x7fffu + ((u >> 16) & 1u);
  return (u16)(r >> 16);
}
__device__ __forceinline__ float bf2f(u16 h) {
  unsigned u = ((unsigned)h) << 16;
  return __builtin_bit_cast(float, u);
}
__device__ __forceinline__ unsigned cvtpk(float lo, float hi) {
  unsigned r;
  asm("v_cvt_pk_bf16_f32 %0, %1, %2" : "=v"(r) : "v"(lo), "v"(hi));
  return r;
}
__device__ __forceinline__ float fexp2(float x) {
  return __builtin_amdgcn_exp2f(x);   // raw v_exp_f32 (args bounded; OCML guards not needed)
}

#define QSCALE 0.1803368801111204f   // 0.125 * log2(e): folded into Q at rope time
#define L2E    1.44269504088896f

// ---------------- x -> bf16 ----------------
__global__ __launch_bounds__(256) void cvt_x(const float* __restrict__ x, u16* __restrict__ xb) {
  int i = blockIdx.x * 256 + threadIdx.x;
  f32x4 v = ((const f32x4*)x)[i];
  u16x4 o = { f2bf(v[0]), f2bf(v[1]), f2bf(v[2]), f2bf(v[3]) };
  ((u16x4*)xb)[i] = o;
}

// ------------- transpose + convert weights: in [K][N] f32 -> out [N][K] bf16 -------------
__global__ __launch_bounds__(256) void transpose_cvt(const float* __restrict__ in, u16* __restrict__ out,
                                                     int K, int N) {
  __shared__ float tile[32][33];
  int n0 = blockIdx.x * 32, k0 = blockIdx.y * 32;
  int tx = threadIdx.x, ty = threadIdx.y; // 32 x 8
#pragma unroll
  for (int i = 0; i < 4; ++i)
    tile[ty + i * 8][tx] = in[(size_t)(k0 + ty + i * 8) * N + n0 + tx];
  __syncthreads();
#pragma unroll
  for (int i = 0; i < 4; ++i)
    out[(size_t)(n0 + ty + i * 8) * K + k0 + tx] = f2bf(tile[tx][ty + i * 8]);
}

// ------------- GEMM: A [M][K] bf16, Bt [N][K] bf16 -> C [M][N] (bf16 or f32) -------------
// m97 layout, BK=64 (32 MFMA per barrier-pair) + T2 XOR swizzle (16-way -> 2-way on
// ds_read_b128): storage chunk s of a row holds logical chunk s^(row&7); applied on the
// global_load_lds SOURCE address (linear LDS dest, rule 21) and on the fragment-read side.
template <int OUTBF>
__global__ __launch_bounds__(256) void gemm_bt(const u16* __restrict__ A, const u16* __restrict__ Bt,
                                               void* __restrict__ Cout, int M, int N, int K) {
  __shared__ u16 As[128 * 64];
  __shared__ u16 Bs[128 * 64];
  const int tid = threadIdx.x;
  const int w = tid >> 6, l = tid & 63, lg = l >> 4, lr = l & 15;
  const int m0 = blockIdx.y * 128, n0 = blockIdx.x * 128;
  const int wr = w >> 1, wc = w & 1;

  // staging: storage chunk c = j*256 + tid; row = c>>3; holds logical chunk (c&7)^(row&7)
  size_t srcA[4], srcB[4];
  int ldst[4];
#pragma unroll
  for (int j = 0; j < 4; ++j) {
    int c = j * 256 + tid;
    int row = c >> 3, kb = (c & 7) ^ (row & 7);
    srcA[j] = (size_t)(m0 + row) * K + kb * 8;
    srcB[j] = (size_t)(n0 + row) * K + kb * 8;
    ldst[j] = (j * 256 + w * 64) * 8;   // wave-uniform element base (lane adds 16B)
  }

  // fragment-read byte offsets: logical chunk kk*4+lg of row -> storage (kk*4+lg)^(lr&7)
  const int lx = lr & 7;
  int aoff[2][4], boff[2][4];
#pragma unroll
  for (int kk = 0; kk < 2; ++kk) {
#pragma unroll
    for (int m = 0; m < 4; ++m)
      aoff[kk][m] = (wr * 64 + m * 16 + lr) * 128 + ((((kk << 2) | lg) ^ lx) << 4);
#pragma unroll
    for (int n = 0; n < 4; ++n)
      boff[kk][n] = (wc * 64 + n * 16 + lr) * 128 + ((((kk << 2) | lg) ^ lx) << 4);
  }

  f32x4 acc[4][4];
#pragma unroll
  for (int m = 0; m < 4; ++m)
#pragma unroll
    for (int n = 0; n < 4; ++n) acc[m][n] = (f32x4){0.f, 0.f, 0.f, 0.f};

  for (int k0 = 0; k0 < K; k0 += 64) {
    __syncthreads();
#pragma unroll
    for (int j = 0; j < 4; ++j) {
      gload16(A + k0 + srcA[j], &As[ldst[j]]);
      gload16(Bt + k0 + srcB[j], &Bs[ldst[j]]);
    }
    __syncthreads();
#pragma unroll
    for (int kk = 0; kk < 2; ++kk) {
      bf16x8 af[4], bf[4];
#pragma unroll
      for (int m = 0; m < 4; ++m)
        af[m] = *(const bf16x8*)((const char*)As + aoff[kk][m]);
#pragma unroll
      for (int n = 0; n < 4; ++n)
        bf[n] = *(const bf16x8*)((const char*)Bs + boff[kk][n]);
      __builtin_amdgcn_s_setprio(1);
#pragma unroll
      for (int m = 0; m < 4; ++m)
#pragma unroll
        for (int n = 0; n < 4; ++n)
          acc[m][n] = __builtin_amdgcn_mfma_f32_16x16x32_bf16(af[m], bf[n], acc[m][n], 0, 0, 0);
      __builtin_amdgcn_s_setprio(0);
    }
  }
#pragma unroll
  for (int m = 0; m < 4; ++m)
#pragma unroll
    for (int n = 0; n < 4; ++n)
#pragma unroll
      for (int r = 0; r < 4; ++r) {
        int row = m0 + wr * 64 + m * 16 + lg * 4 + r;
        int col = n0 + wc * 64 + n * 16 + lr;
        float v = acc[m][n][r];
        if (OUTBF)
          ((u16*)Cout)[(size_t)row * N + col] = f2bf(v);
        else
          ((float*)Cout)[(size_t)row * N + col] = v;
      }
}

// ------------- RoPE (K only now): qkv [4096][3072] bf16 -> dst [B][nh][S][64] bf16 -------------
__global__ __launch_bounds__(256) void rope_kernel(const u16* __restrict__ qkv, const float* __restrict__ fcos,
                                                   const float* __restrict__ fsin, u16* __restrict__ dst,
                                                   int nhs /*log2 nheads*/, int col0, float scale) {
  int idx = blockIdx.x * 256 + threadIdx.x;
  int p = idx & 31;
  int h = (idx >> 5) & ((1 << nhs) - 1);
  int t = idx >> (5 + nhs);
  int s = t & 2047, b = t >> 11;
  unsigned v = *(const unsigned*)(qkv + (size_t)t * 3072 + col0 + h * 64 + 2 * p);
  float xr = bf2f((u16)(v & 0xffff)), xi = bf2f((u16)(v >> 16));
  float c = fcos[s * 32 + p], sn = fsin[s * 32 + p];
  float orr = (xr * c - xi * sn) * scale;
  float oii = (xr * sn + xi * c) * scale;
  unsigned o = (unsigned)f2bf(orr) | ((unsigned)f2bf(oii) << 16);
  *(unsigned*)(dst + (((size_t)((b << nhs) + h) * 2048 + s) * 64 + 2 * p)) = o;
}

// ------------- V transpose: qkv cols [2560..3072) -> vT [(b*8+kv)*64+d][S] -------------
// Token (key) columns are PERMUTED within each 16-group (swap bits 2<->3) so that a
// contiguous 16B chunk holds keys in MFMA B-operand slot order (j&3)+8*(j>>2)+4*hi.
__global__ __launch_bounds__(256) void vtrans(const u16* __restrict__ qkv, u16* __restrict__ vT) {
  __shared__ u16 tile[32][33];
  int c0 = blockIdx.x * 32, t0 = blockIdx.y * 32;
  int tx = threadIdx.x, ty = threadIdx.y;
#pragma unroll
  for (int i = 0; i < 4; ++i)
    tile[ty + i * 8][tx] = qkv[(size_t)(t0 + ty + i * 8) * 3072 + 2560 + c0 + tx];
  __syncthreads();
#pragma unroll
  for (int i = 0; i < 4; ++i) {
    int c = c0 + ty + i * 8;
    int tok = t0 + tx;
    int ts = (tok & ~15) | (tok & 3) | ((tok & 4) << 1) | ((tok & 8) >> 1); // swap bits 2,3
    vT[((size_t)((tok >> 11) * 8 + (c >> 6)) * 64 + (c & 63)) * 2048 + (ts & 2047)] = tile[tx][ty + i * 8];
  }
}

// ------------- mask tile flags: Fl[qt] bit kt = (128q x 64k tile has any nonzero) -------------
__global__ __launch_bounds__(256) void mask_flags(const float* __restrict__ mask, unsigned* __restrict__ Fl) {
  int qt = blockIdx.x, kt = blockIdx.y;
  int t = threadIdx.x;
  int row = qt * 128 + (t >> 1);
  const f32x4* p = (const f32x4*)(mask + (size_t)row * 2048 + kt * 64 + (t & 1) * 32);
  bool any = false;
#pragma unroll
  for (int j = 0; j < 8; ++j) {
    f32x4 v = p[j];
    any |= (v[0] != 0.f) | (v[1] != 0.f) | (v[2] != 0.f) | (v[3] != 0.f);
  }
  if (__any(any) && (t & 63) == 0) atomicOr(&Fl[qt], 1u << kt);
}

// ------------- Flash attention: swapped-QK 32x32 MFMA, MAXLESS softmax -------------
// Q is read RAW from qkv (gemm1 output) and RoPE+QSCALE is applied in-register in the
// prologue (pairs (2p,2p+1) are lane-local; identical rounding chain to the old rope_q).
// p = exp2(a - mrun2) directly (mrun2==0 ~always). Mask folds as a += mk*L2E.
__global__ __launch_bounds__(256, 4) void attn(const u16* __restrict__ QKVraw,
                                               const float* __restrict__ fcos, const float* __restrict__ fsin,
                                               const u16* __restrict__ Kb, const u16* __restrict__ Vt,
                                               const float* __restrict__ mask,
                                               const unsigned* __restrict__ Fl, u16* __restrict__ Ao) {
  __shared__ u16 Ks[2][4096];
  __shared__ u16 Vs[2][4096];
  const int bid = blockIdx.x;
  const int qt = bid & 15, h = (bid >> 4) & 31, b = bid >> 9;
  const int kv = h >> 2;
  const int tid = threadIdx.x, w = tid >> 6, l = tid & 63;
  const int lq = l & 31, hi = l >> 5;

  // ---- Q fragments: raw from qkv + in-register RoPE (+QSCALE) ----
  const int srowq = qt * 128 + w * 32 + lq;
  const u16* Qb = QKVraw + (size_t)(b * 2048 + srowq) * 3072 + h * 64;
  bf16x8 qf[4];
#pragma unroll
  for (int t = 0; t < 4; ++t) {
    bf16x8 qr = *(const bf16x8*)(Qb + t * 16 + hi * 8);
    u32x4 qw = __builtin_bit_cast(u32x4, qr);
    f32x4 cc = *(const f32x4*)(fcos + srowq * 32 + t * 8 + hi * 4);
    f32x4 ss = *(const f32x4*)(fsin + srowq * 32 + t * 8 + hi * 4);
    u32x4 ow;
#pragma unroll
    for (int j = 0; j < 4; ++j) {
      unsigned wrd = qw[j];
      float xr = bf2f((u16)(wrd & 0xffff)), xi = bf2f((u16)(wrd >> 16));
      float orr = (xr * cc[j] - xi * ss[j]) * QSCALE;
      float oii = (xr * ss[j] + xi * cc[j]) * QSCALE;
      ow[j] = cvtpk(orr, oii);
    }
    qf[t] = __builtin_bit_cast(bf16x8, ow);
  }

  const u16* Ksrc = Kb + (size_t)(b * 8 + kv) * 2048 * 64;
  const u16* Vsrc = Vt + (size_t)(b * 8 + kv) * 64 * 2048;
  const float* Mrow = mask + (size_t)srowq * 2048;
  const unsigned flagbits = Fl[qt];

  const int lx = lq & 7;
  int koff[8];
#pragma unroll
  for (int ks = 0; ks < 2; ++ks)
#pragma unroll
    for (int t = 0; t < 4; ++t)
      koff[ks * 4 + t] = (lq + 32 * ks) * 128 + ((((t << 1) + hi) ^ lx) << 4);
  int voff[8];
#pragma unroll
  for (int ks = 0; ks < 2; ++ks)
#pragma unroll
    for (int t = 0; t < 2; ++t)
#pragma unroll
      for (int dblk = 0; dblk < 2; ++dblk)
        voff[(ks * 2 + t) * 2 + dblk] =
            (lq + 32 * dblk) * 128 + ((((ks << 2) + (t << 1) + hi) ^ lx) << 4);

  size_t kgoff[2], vgoff[2];
  int ldso[2];
#pragma unroll
  for (int j = 0; j < 2; ++j) {
    int c = w * 64 + j * 256 + l;
    int row = c >> 3;
    int sc_ = ((c & 7) ^ (row & 7)) * 8;
    kgoff[j] = (size_t)row * 64 + sc_;
    vgoff[j] = (size_t)row * 2048 + sc_;
    ldso[j] = (w * 64 + j * 256) * 8;
  }

  f32x16 o0, o1, zacc;
#pragma unroll
  for (int i = 0; i < 16; ++i) { o0[i] = 0.f; o1[i] = 0.f; zacc[i] = 0.f; }
  float mrun2 = 0.f, lrun = 0.f;

  auto stage = [&](int kt2, int bu2) {
#pragma unroll
    for (int j = 0; j < 2; ++j) {
      gload16(Ksrc + (size_t)kt2 * 4096 + kgoff[j], &Ks[bu2][ldso[j]]);
      gload16(Vsrc + (size_t)kt2 * 64 + vgoff[j], &Vs[bu2][ldso[j]]);
    }
  };

  stage(0, 0);
  __syncthreads();

  for (int kt = 0; kt < 32; ++kt) {
    const int bu = kt & 1;
    if (kt < 31) stage(kt + 1, bu ^ 1);
    const char* KL = (const char*)Ks[bu];
    const char* VL = (const char*)Vs[bu];
    const bool havemask = (flagbits >> kt) & 1;

#pragma unroll
    for (int ks = 0; ks < 2; ++ks) {
      // ---- QK^T swapped: a[k][q] = sum_d K[k][d] (C*Q[q][d])  (pre-scaled) ----
      __builtin_amdgcn_s_setprio(1);
      bf16x8 kf = *(const bf16x8*)(KL + koff[ks * 4]);
      f32x16 a = __builtin_amdgcn_mfma_f32_32x32x16_bf16(kf, qf[0], zacc, 0, 0, 0);
#pragma unroll
      for (int t = 1; t < 4; ++t) {
        kf = *(const bf16x8*)(KL + koff[ks * 4 + t]);
        a = __builtin_amdgcn_mfma_f32_32x32x16_bf16(kf, qf[t], a, 0, 0, 0);
      }
      __builtin_amdgcn_s_setprio(0);

      // ---- rare path: fold mask (a += mk * log2e) ----
      if (havemask) {
#pragma unroll
        for (int g = 0; g < 4; ++g) {
          f32x4 mk = *(const f32x4*)(Mrow + kt * 64 + ks * 32 + g * 8 + hi * 4);
#pragma unroll
          for (int i = 0; i < 4; ++i) a[g * 4 + i] = fmaf(mk[i], L2E, a[g * 4 + i]);
        }
      }

      // ---- p = exp2(a - mrun2); direct exp when mrun2==0 (~always) ----
      float ps0 = 0.f, ps1 = 0.f, ps2 = 0.f, ps3 = 0.f;
      if (mrun2 == 0.f) {
#pragma unroll
        for (int i = 0; i < 16; i += 4) {
          float p0 = fexp2(a[i]);
          float p1 = fexp2(a[i + 1]);
          float p2 = fexp2(a[i + 2]);
          float p3 = fexp2(a[i + 3]);
          a[i] = p0; a[i + 1] = p1; a[i + 2] = p2; a[i + 3] = p3;
          ps0 += p0; ps1 += p1; ps2 += p2; ps3 += p3;
        }
      } else {
#pragma unroll
        for (int i = 0; i < 16; i += 4) {
          float p0 = fexp2(a[i] - mrun2);
          float p1 = fexp2(a[i + 1] - mrun2);
          float p2 = fexp2(a[i + 2] - mrun2);
          float p3 = fexp2(a[i + 3] - mrun2);
          a[i] = p0; a[i + 1] = p1; a[i + 2] = p2; a[i + 3] = p3;
          ps0 += p0; ps1 += p1; ps2 += p2; ps3 += p3;
        }
      }
      lrun += (ps0 + ps1) + (ps2 + ps3);

      // ---- P -> bf16 (lane-resident; slot j = key (j&3)+8*(j>>2)+4hi), PV via b128 V reads ----
      unsigned uu0 = cvtpk(a[0], a[1]);
      unsigned uu1 = cvtpk(a[2], a[3]);
      unsigned uu2 = cvtpk(a[4], a[5]);
      unsigned uu3 = cvtpk(a[6], a[7]);
      unsigned uu4 = cvtpk(a[8], a[9]);
      unsigned uu5 = cvtpk(a[10], a[11]);
      unsigned uu6 = cvtpk(a[12], a[13]);
      unsigned uu7 = cvtpk(a[14], a[15]);
      __builtin_amdgcn_s_setprio(1);
#pragma unroll
      for (int t = 0; t < 2; ++t) {
        u32x4 wv_;
        if (t == 0) wv_ = (u32x4){uu0, uu1, uu2, uu3};
        else        wv_ = (u32x4){uu4, uu5, uu6, uu7};
        bf16x8 pa = __builtin_bit_cast(bf16x8, wv_);
#pragma unroll
        for (int dblk = 0; dblk < 2; ++dblk) {
          bf16x8 vfrag = *(const bf16x8*)(VL + voff[(ks * 2 + t) * 2 + dblk]);
          if (dblk == 0) o0 = __builtin_amdgcn_mfma_f32_32x32x16_bf16(pa, vfrag, o0, 0, 0, 0);
          else           o1 = __builtin_amdgcn_mfma_f32_32x32x16_bf16(pa, vfrag, o1, 0, 0, 0);
        }
      }
      __builtin_amdgcn_s_setprio(0);
    }

    // ---- overflow guard (wave-uniform, ~never taken): shift scale by 2^-64 ----
    if (__builtin_expect(__any(lrun > 1.0e27f), 0)) {
      const float DS = 5.421010862427522e-20f;  // 2^-64
      mrun2 += 64.0f;
      lrun *= DS;
#pragma unroll
      for (int r = 0; r < 16; ++r) { o0[r] *= DS; o1[r] *= DS; }
    }

    __syncthreads();
  }

  // ---- epilogue: cross-half sum once; 1/lrun broadcast via shfl (lane lq holds row lq) ----
  lrun += __shfl_xor(lrun, 32);
  float linv = 1.0f / lrun;
#pragma unroll
  for (int r = 0; r < 16; ++r) {
    int oq = (r & 3) + 8 * (r >> 2) + 4 * hi;
    float inv = __shfl(linv, oq);
    int srow = qt * 128 + w * 32 + oq;
    size_t tok = (size_t)(b * 2048 + srow);
    Ao[tok * 2048 + h * 64 + lq]      = f2bf(o0[r] * inv);
    Ao[tok * 2048 + h * 64 + 32 + lq] = f2bf(o1[r] * inv);
  }
}

extern "C" void kernel_launch(void* const* d_in, const int* in_sizes, int n_in,
                              void* d_out, int out_size, void* d_ws, size_t ws_size,
                              hipStream_t stream) {
  const float* x    = (const float*)d_in[0];
  const float* fcos = (const float*)d_in[1];
  const float* fsin = (const float*)d_in[2];
  const float* mask = (const float*)d_in[3];
  const float* wq   = (const float*)d_in[4];
  const float* wk   = (const float*)d_in[5];
  const float* wv   = (const float*)d_in[6];
  const float* wo   = (const float*)d_in[7];
  float* out = (float*)d_out;

  // workspace layout (u16 elements), total ~79.7 MB
  u16* ws  = (u16*)d_ws;
  u16* xb  = ws;                       // 8,388,608   x bf16; later reused as attn_out
  u16* wT  = ws + 8388608;             // 6,291,456   wqkvT [3072][2048]; later woT [2048][2048]
  u16* qkv = ws + 14680064;            // 12,582,912  qkv [4096][3072] (q raw / k raw / v)
  u16* kb  = ws + 35651584;            // 2,097,152   K [B][8][S][64]  (rope'd)
  u16* vT  = ws + 37748736;            // 2,097,152   V^T [B*8][64][S] (token cols permuted)
  // Fl: 16 u32 at the head of the (now unused) qb region
  unsigned* Fl = (unsigned*)(ws + 27262976);

  cvt_x<<<8192, 256, 0, stream>>>(x, xb);
  transpose_cvt<<<dim3(64, 64), dim3(32, 8), 0, stream>>>(wq, wT, 2048, 2048);
  transpose_cvt<<<dim3(16, 64), dim3(32, 8), 0, stream>>>(wk, wT + (size_t)2048 * 2048, 2048, 512);
  transpose_cvt<<<dim3(16, 64), dim3(32, 8), 0, stream>>>(wv, wT + (size_t)2560 * 2048, 2048, 512);
  gemm_bt<1><<<dim3(24, 32), 256, 0, stream>>>(xb, wT, qkv, 4096, 3072, 2048);
  transpose_cvt<<<dim3(64, 64), dim3(32, 8), 0, stream>>>(wo, wT, 2048, 2048);  // woT (wT reuse)
  rope_kernel<<<4096, 256, 0, stream>>>(qkv, fcos, fsin, kb, 3, 2048, 1.0f);
  vtrans<<<dim3(16, 128), dim3(32, 8), 0, stream>>>(qkv, vT);
  hipMemsetAsync(Fl, 0, 16 * sizeof(unsigned), stream);
  mask_flags<<<dim3(16, 32), 256, 0, stream>>>(mask, Fl);
  attn<<<1024, 256, 0, stream>>>(qkv, fcos, fsin, kb, vT, mask, Fl, xb);
  gemm_bt<0><<<dim3(16, 32), 256, 0, stream>>>(xb, wT, out, 4096, 2048, 2048);
}